// Round 4
// baseline (121.132 us; speedup 1.0000x reference)
//
#include <hip/hip_runtime.h>
#include <hip/hip_fp16.h>

typedef _Float16 f16;
typedef _Float16 half8 __attribute__((ext_vector_type(8)));
typedef float f32x4 __attribute__((ext_vector_type(4)));

#define BATCH 8
#define NTOK 2048
#define FIN 256
#define FOUT 256
#define ALPHA 0.2f
#define WHS 2080   // WhT row stride (pad breaks 4KB power-of-2 stride)

// ---------------- K0: W[k][o] fp32 -> WT[o][k] fp16 ----------------
__global__ void k_wt(const float* __restrict__ W, f16* __restrict__ WT) {
    __shared__ float t[32][33];
    int o0 = blockIdx.x * 32, k0 = blockIdx.y * 32;
    int tx = threadIdx.x, ty = threadIdx.y;
    t[ty][tx] = W[(k0 + ty) * FOUT + o0 + tx];
    __syncthreads();
    WT[(o0 + ty) * FIN + (k0 + tx)] = (f16)t[tx][ty];
}

// ---------------- K pack: adj int32 -> bitmask ----------------
__global__ __launch_bounds__(256) void k_pack(const int* __restrict__ adj,
                                              unsigned long long* __restrict__ mask) {
    int lane = threadIdx.x & 63;
    size_t wv = (((size_t)blockIdx.x * 256 + threadIdx.x) >> 6);
    for (int it = 0; it < 8; it++) {
        size_t wave = wv + (size_t)it * 16384;
        const int* base = adj + wave * 256;
        unsigned long long m0 = __ballot(base[lane] > 0);
        unsigned long long m1 = __ballot(base[64 + lane] > 0);
        unsigned long long m2 = __ballot(base[128 + lane] > 0);
        unsigned long long m3 = __ballot(base[192 + lane] > 0);
        if (lane < 4) {
            unsigned long long v = lane == 0 ? m0 : lane == 1 ? m1 : lane == 2 ? m2 : m3;
            mask[wave * 4 + lane] = v;
        }
    }
}

// ---------------- K1: Wh = x @ W, store WhT[b][o][n] fp16 ----------------
__global__ __launch_bounds__(256) void k_gemm(const float* __restrict__ x,
                                              const f16* __restrict__ WT,
                                              f16* __restrict__ WhT) {
    __shared__ f16 Ah[64][72];
    __shared__ f16 Bt[256][72];
    int m0 = blockIdx.x * 64;
    int t = threadIdx.x;
    int lane = t & 63, w = t >> 6;
    f32x4 acc[4][4] = {};

    for (int k0 = 0; k0 < FIN; k0 += 64) {
        {
            int r = t >> 2, c = (t & 3) * 16;
            const float* src = x + (size_t)(m0 + r) * FIN + k0 + c;
            f16 tmp[16];
#pragma unroll
            for (int q = 0; q < 16; q++) tmp[q] = (f16)src[q];
            *(half8*)&Ah[r][c] = *(half8*)&tmp[0];
            *(half8*)&Ah[r][c + 8] = *(half8*)&tmp[8];
        }
        {
            const f16* src = WT + (size_t)t * FIN + k0;
#pragma unroll
            for (int q = 0; q < 8; q++)
                *(half8*)&Bt[t][q * 8] = *(const half8*)&src[q * 8];
        }
        __syncthreads();
#pragma unroll
        for (int kc = 0; kc < 2; kc++) {
            int krow = kc * 32 + ((lane >> 4) * 8);
            half8 af[4], bf[4];
#pragma unroll
            for (int fi = 0; fi < 4; fi++)
                af[fi] = *(half8*)&Ah[fi * 16 + (lane & 15)][krow];
#pragma unroll
            for (int fo = 0; fo < 4; fo++)
                bf[fo] = *(half8*)&Bt[w * 64 + fo * 16 + (lane & 15)][krow];
#pragma unroll
            for (int fi = 0; fi < 4; fi++)
#pragma unroll
                for (int fo = 0; fo < 4; fo++)
                    acc[fi][fo] = __builtin_amdgcn_mfma_f32_16x16x32_f16(
                        af[fi], bf[fo], acc[fi][fo], 0, 0, 0);
        }
        __syncthreads();
    }
    int b = m0 >> 11;
    int nbase = m0 & (NTOK - 1);
#pragma unroll
    for (int fi = 0; fi < 4; fi++)
#pragma unroll
        for (int fo = 0; fo < 4; fo++) {
            int o = w * 64 + fo * 16 + (lane & 15);
#pragma unroll
            for (int q = 0; q < 4; q++) {
                int n = nbase + fi * 16 + (lane >> 4) * 4 + q;
                WhT[((size_t)b * FOUT + o) * WHS + n] = (f16)acc[fi][fo][q];
            }
        }
}

// ---------------- K2: s1 = Wh@a1, s2 = Wh@a2 ----------------
__global__ __launch_bounds__(256) void k_s12(const f16* __restrict__ WhT,
                                             const float* __restrict__ a,
                                             float* __restrict__ s1,
                                             float* __restrict__ s2) {
    int b = blockIdx.y;
    int n = blockIdx.x * 256 + threadIdx.x;
    const f16* base = WhT + (size_t)b * FOUT * WHS + n;
    float a1 = 0.f, a2 = 0.f;
#pragma unroll 4
    for (int o = 0; o < FOUT; o++) {
        float wh = (float)base[(size_t)o * WHS];
        a1 += wh * a[o];
        a2 += wh * a[FOUT + o];
    }
    s1[b * NTOK + n] = a1;
    s2[b * NTOK + n] = a2;
}

// ---------------- K3: fused masked softmax + P@Wh + ELU ----------------
// Block: 512 thr = 8 waves. wave w: rg=w&1 (32-row group), oh=(w>>1)&1 (128-col
// half), jg=w>>2 (1024-j half). Each wave: P built in-register in MFMA A-layout
// (2 row-tiles), zero barriers in main loop. j-halves flash-combined via LDS.
__global__ __launch_bounds__(512, 2) void k_attn(const unsigned* __restrict__ mask,
                                                 const f16* __restrict__ WhT,
                                                 const float* __restrict__ s1g,
                                                 const float* __restrict__ s2g,
                                                 float* __restrict__ out) {
    __shared__ float s2_lds[NTOK];
    __shared__ float accx[64][132];       // combine staging, 2 rounds of 128 cols
    __shared__ float ml_lds[2][2][64];    // [jg][m|l][row]

    int b = blockIdx.x & 7;               // batch -> XCD pinning
    int i0 = (blockIdx.x >> 3) * 64;
    int t = threadIdx.x;
    int lane = t & 63;
    int w = t >> 6;
    int rg = w & 1;
    int oh = (w >> 1) & 1;
    int jg = w >> 2;
    int lr = lane & 15;
    int lg = lane >> 4;

    ((f32x4*)s2_lds)[t] = ((const f32x4*)(s2g + (size_t)b * NTOK))[t];
    __syncthreads();

    int row0 = i0 + rg * 32 + lr;         // fi=0 absolute row in batch
    float s1r0 = s1g[(size_t)b * NTOK + row0];
    float s1r1 = s1g[(size_t)b * NTOK + row0 + 16];

    float m0 = -3.0e38f, l0 = 0.f, m1 = -3.0e38f, l1 = 0.f;
    f32x4 acc0[8] = {}, acc1[8] = {};

    const int4* mrow0 = (const int4*)(mask + ((size_t)(b * NTOK + row0)) * 64 + jg * 32);
    const int4* mrow1 = (const int4*)(mask + ((size_t)(b * NTOK + row0 + 16)) * 64 + jg * 32);
    const f16* wbase = WhT + ((size_t)(b * FOUT + oh * 128 + lr)) * WHS + jg * 1024 + lg * 8;

    int4 mn0 = mrow0[0], mn1 = mrow1[0];

    for (int jt = 0; jt < 8; jt++) {
        int4 mw0 = mn0, mw1 = mn1;
        if (jt < 7) { mn0 = mrow0[jt + 1]; mn1 = mrow1[jt + 1]; }

        int sbase = jg * 1024 + jt * 128 + lg * 8;
        f32x4 sv[4][2];
#pragma unroll
        for (int kc = 0; kc < 4; kc++) {
            sv[kc][0] = *(const f32x4*)&s2_lds[sbase + kc * 32];
            sv[kc][1] = *(const f32x4*)&s2_lds[sbase + kc * 32 + 4];
        }

        half8 ph0[4], ph1[4];
        float scl0, scl1;
        {   // fi = 0
            unsigned wk[4] = {(unsigned)mw0.x, (unsigned)mw0.y, (unsigned)mw0.z, (unsigned)mw0.w};
            float e[4][8];
            float lm = -3.0e38f;
#pragma unroll
            for (int kc = 0; kc < 4; kc++) {
                unsigned bits = (wk[kc] >> (lg * 8)) & 0xffu;
#pragma unroll
                for (int q = 0; q < 8; q++) {
                    float sum = s1r0 + sv[kc][q >> 2][q & 3];
                    float ev = fmaxf(sum, ALPHA * sum);
                    e[kc][q] = ev;
                    lm = fmaxf(lm, ((bits >> q) & 1) ? ev : -3.0e38f);
                }
            }
            lm = fmaxf(lm, __shfl_xor(lm, 16));
            lm = fmaxf(lm, __shfl_xor(lm, 32));
            float mn = fmaxf(m0, lm);
            scl0 = __expf(m0 - mn);
            float ts = 0.f;
#pragma unroll
            for (int kc = 0; kc < 4; kc++) {
                unsigned bits = (wk[kc] >> (lg * 8)) & 0xffu;
#pragma unroll
                for (int q = 0; q < 8; q++) {
                    float p = ((bits >> q) & 1) ? __expf(e[kc][q] - mn) : 0.f;
                    ts += p;
                    ph0[kc][q] = (f16)p;
                }
            }
            ts += __shfl_xor(ts, 16);
            ts += __shfl_xor(ts, 32);
            l0 = l0 * scl0 + ts;
            m0 = mn;
        }
        {   // fi = 1
            unsigned wk[4] = {(unsigned)mw1.x, (unsigned)mw1.y, (unsigned)mw1.z, (unsigned)mw1.w};
            float e[4][8];
            float lm = -3.0e38f;
#pragma unroll
            for (int kc = 0; kc < 4; kc++) {
                unsigned bits = (wk[kc] >> (lg * 8)) & 0xffu;
#pragma unroll
                for (int q = 0; q < 8; q++) {
                    float sum = s1r1 + sv[kc][q >> 2][q & 3];
                    float ev = fmaxf(sum, ALPHA * sum);
                    e[kc][q] = ev;
                    lm = fmaxf(lm, ((bits >> q) & 1) ? ev : -3.0e38f);
                }
            }
            lm = fmaxf(lm, __shfl_xor(lm, 16));
            lm = fmaxf(lm, __shfl_xor(lm, 32));
            float mn = fmaxf(m1, lm);
            scl1 = __expf(m1 - mn);
            float ts = 0.f;
#pragma unroll
            for (int kc = 0; kc < 4; kc++) {
                unsigned bits = (wk[kc] >> (lg * 8)) & 0xffu;
#pragma unroll
                for (int q = 0; q < 8; q++) {
                    float p = ((bits >> q) & 1) ? __expf(e[kc][q] - mn) : 0.f;
                    ts += p;
                    ph1[kc][q] = (f16)p;
                }
            }
            ts += __shfl_xor(ts, 16);
            ts += __shfl_xor(ts, 32);
            l1 = l1 * scl1 + ts;
            m1 = mn;
        }

        // rescale accumulators (acc row = lg*4+q within each 16-row tile)
        f32x4 r0, r1;
#pragma unroll
        for (int q = 0; q < 4; q++) {
            r0[q] = __shfl(scl0, lg * 4 + q);
            r1[q] = __shfl(scl1, lg * 4 + q);
        }
#pragma unroll
        for (int ot = 0; ot < 8; ot++) { acc0[ot] *= r0; acc1[ot] *= r1; }

        const f16* wj = wbase + jt * 128;
#pragma unroll
        for (int ot = 0; ot < 8; ot++) {
            const f16* wo = wj + (size_t)ot * 16 * WHS;
            half8 b0 = *(const half8*)(wo);
            half8 b1 = *(const half8*)(wo + 32);
            half8 b2 = *(const half8*)(wo + 64);
            half8 b3 = *(const half8*)(wo + 96);
            acc0[ot] = __builtin_amdgcn_mfma_f32_16x16x32_f16(ph0[0], b0, acc0[ot], 0, 0, 0);
            acc1[ot] = __builtin_amdgcn_mfma_f32_16x16x32_f16(ph1[0], b0, acc1[ot], 0, 0, 0);
            acc0[ot] = __builtin_amdgcn_mfma_f32_16x16x32_f16(ph0[1], b1, acc0[ot], 0, 0, 0);
            acc1[ot] = __builtin_amdgcn_mfma_f32_16x16x32_f16(ph1[1], b1, acc1[ot], 0, 0, 0);
            acc0[ot] = __builtin_amdgcn_mfma_f32_16x16x32_f16(ph0[2], b2, acc0[ot], 0, 0, 0);
            acc1[ot] = __builtin_amdgcn_mfma_f32_16x16x32_f16(ph1[2], b2, acc1[ot], 0, 0, 0);
            acc0[ot] = __builtin_amdgcn_mfma_f32_16x16x32_f16(ph0[3], b3, acc0[ot], 0, 0, 0);
            acc1[ot] = __builtin_amdgcn_mfma_f32_16x16x32_f16(ph1[3], b3, acc1[ot], 0, 0, 0);
        }
    }

    if (oh == 0 && lane < 16) {
        ml_lds[jg][0][rg * 32 + lane] = m0;
        ml_lds[jg][1][rg * 32 + lane] = l0;
        ml_lds[jg][0][rg * 32 + 16 + lane] = m1;
        ml_lds[jg][1][rg * 32 + 16 + lane] = l1;
    }
    __syncthreads();

    // flash combine, 2 rounds of 4 o-tiles (LDS 64x128 staging per round)
#pragma unroll
    for (int c = 0; c < 2; c++) {
        if (jg == 1) {
#pragma unroll
            for (int fi = 0; fi < 2; fi++)
#pragma unroll
                for (int q = 0; q < 4; q++) {
                    int rr = rg * 32 + fi * 16 + lg * 4 + q;
                    float ma = ml_lds[0][0][rr], mb = ml_lds[1][0][rr];
                    float f1 = __expf(mb - fmaxf(ma, mb));
#pragma unroll
                    for (int ol = 0; ol < 4; ol++) {
                        int ot = c * 4 + ol;
                        float v = (fi ? acc1[ot][q] : acc0[ot][q]) * f1;
                        accx[rr][oh * 64 + ol * 16 + lr] = v;
                    }
                }
        }
        __syncthreads();
        if (jg == 0) {
#pragma unroll
            for (int fi = 0; fi < 2; fi++)
#pragma unroll
                for (int q = 0; q < 4; q++) {
                    int rr = rg * 32 + fi * 16 + lg * 4 + q;
                    float ma = ml_lds[0][0][rr], mb = ml_lds[1][0][rr];
                    float mt = fmaxf(ma, mb);
                    float f0 = __expf(ma - mt), f1 = __expf(mb - mt);
                    float lt = ml_lds[0][1][rr] * f0 + ml_lds[1][1][rr] * f1;
                    float rl = 1.f / lt;
#pragma unroll
                    for (int ol = 0; ol < 4; ol++) {
                        int ot = c * 4 + ol;
                        int o = oh * 128 + ot * 16 + lr;
                        float v = ((fi ? acc1[ot][q] : acc0[ot][q]) * f0 +
                                   accx[rr][oh * 64 + ol * 16 + lr]) * rl;
                        v = v > 0.f ? v : __expf(v) - 1.f;
                        __builtin_nontemporal_store(
                            v, &out[((size_t)(b * NTOK + i0 + rr)) * FOUT + o]);
                    }
                }
        }
        __syncthreads();
    }
}

extern "C" void kernel_launch(void* const* d_in, const int* in_sizes, int n_in,
                              void* d_out, int out_size, void* d_ws, size_t ws_size,
                              hipStream_t stream) {
    const float* x = (const float*)d_in[0];
    const int* adj = (const int*)d_in[1];
    const float* W = (const float*)d_in[2];
    const float* a = (const float*)d_in[3];
    float* out = (float*)d_out;

    char* ws = (char*)d_ws;
    f16* WT = (f16*)ws;                                     // 128 KB
    f16* WhT = (f16*)(ws + 131072);                         // 8.13 MB
    float* s1 = (float*)(ws + 131072 + 8519680);            // 64 KB
    float* s2 = s1 + BATCH * NTOK;                          // 64 KB
    unsigned long long* mask64 =
        (unsigned long long*)(ws + 131072 + 8519680 + 131072);  // 4 MB

    k_wt<<<dim3(FOUT / 32, FIN / 32), dim3(32, 32), 0, stream>>>(W, WT);
    k_gemm<<<dim3(BATCH * NTOK / 64), 256, 0, stream>>>(x, WT, WhT);
    k_s12<<<dim3(NTOK / 256, BATCH), 256, 0, stream>>>(WhT, a, s1, s2);
    k_pack<<<dim3(4096), 256, 0, stream>>>(adj, mask64);
    k_attn<<<dim3(BATCH * NTOK / 64), 512, 0, stream>>>((const unsigned*)mask64, WhT, s1, s2, out);
}